// Round 14
// baseline (216.166 us; speedup 1.0000x reference)
//
#include <hip/hip_runtime.h>
#include <cstdint>

typedef short bf16x8 __attribute__((ext_vector_type(8)));
typedef float f32x4  __attribute__((ext_vector_type(4)));

#define TOK    32         // tokens per block -> grid 1024 -> 4 blocks/CU capacity
#define CH     32         // codes per chunk
#define NCH    32         // chunks (K=1024)
#define BUFW   8192       // ushorts per chunk buffer (32 rows x 256 = 16 KB)
#define MAXC   32

__device__ __forceinline__ unsigned short f2bf(float f) {
  unsigned u = __float_as_uint(f);
  return (unsigned short)((u + 0x7FFFu + ((u >> 16) & 1u)) >> 16);
}
__device__ __forceinline__ uint4 pack8(float4 a, float4 b) {
  uint4 u;
  u.x = (unsigned)f2bf(a.x) | ((unsigned)f2bf(a.y) << 16);
  u.y = (unsigned)f2bf(a.z) | ((unsigned)f2bf(a.w) << 16);
  u.z = (unsigned)f2bf(b.x) | ((unsigned)f2bf(b.y) << 16);
  u.w = (unsigned)f2bf(b.z) | ((unsigned)f2bf(b.w) << 16);
  return u;
}
// async global->LDS DMA, 16 B per lane. LDS dest = wave-uniform base + lane*16.
__device__ __forceinline__ void gload16(const unsigned short* g, unsigned short* l) {
  __builtin_amdgcn_global_load_lds(
      (const __attribute__((address_space(1))) unsigned int*)(const void*)g,
      (__attribute__((address_space(3))) unsigned int*)(void*)l, 16, 0, 0);
}

// ---------------------------------------------------------------------------
// Prep: cb_bf = bf16(cb), ee = ||cb_k||^2. Block 0 zeroes global accumulators.
// ---------------------------------------------------------------------------
__global__ __launch_bounds__(256) void vq_prep(const float* __restrict__ cb,
                                               unsigned short* __restrict__ cb_bf,
                                               float* __restrict__ ee,
                                               float* __restrict__ acc2,
                                               int* __restrict__ done_ctr, int K) {
  if (blockIdx.x == 0 && threadIdx.x == 0) {
    acc2[0] = 0.f; acc2[1] = 0.f; *done_ctr = 0;
  }
  int wave = threadIdx.x >> 6, lane = threadIdx.x & 63;
  int k = blockIdx.x * 4 + wave;
  if (k >= K) return;
  float4 v = *reinterpret_cast<const float4*>(cb + (size_t)k * 256 + lane * 4);
  float s = v.x * v.x + v.y * v.y + v.z * v.z + v.w * v.w;
  #pragma unroll
  for (int off = 32; off; off >>= 1) s += __shfl_down(s, off, 64);
  ushort4 b;
  b.x = f2bf(v.x); b.y = f2bf(v.y); b.z = f2bf(v.z); b.w = f2bf(v.w);
  *reinterpret_cast<ushort4*>(cb_bf + (size_t)k * 256 + lane * 4) = b;
  if (lane == 0) ee[k] = s;
}

// ---------------------------------------------------------------------------
// Main: 256 thr (4 waves), TOK=32, grid 1024, LDS ~37 KB -> 4 blocks/CU
// = 16 waves/CU = 4 waves/SIMD. The LAST structural cell: R12's residual is
// per-wave dependent-chain serialization that 2 waves/SIMD can't interleave
// (VALU 27%, all else idle). Prior TLP attempts were each poisoned: R1
// (512-thr spill), R2 (grid 512 caps at 2/CU), R6 ((256,4) VGPR crush to 52
// + serial staging). This config removes ALL known poisons:
//  - (256,2) launch bounds (no crush; VGPR ~100 <= 128 still allows 4/SIMD)
//  - async dbuf global_load_lds staging, ONE barrier per chunk (R11 pattern)
//  - R12's register screen: swapped-operand MFMA 16x16x32 (mfma(codes,
//    tokens): col=token, row=code) -> each lane holds 4 codes of ONE token
//    -> 4 register fmins + one 4-way atomicMin + one gate read per chunk
//  - ee evicted to GLOBAL (L1-resident 4 KB) to fit the 40 KB LDS budget
//  - R11 two-tier epilogue verbatim (tier-1 skip proven -13 us)
// Wave (ts=wv&1, cs=wv>>1): tokens [16ts,16ts+16) x codes [16cs,16cs+16) of
// each 32-code chunk; 8 MFMAs/chunk/wave; tfrag = 32 VGPR.
// NOTE R13 bench was an infra failure (container acquire failed; no pytest,
// no counters) — kernel statically re-audited (bounds, fragment maps, race
// freedom) and resubmitted unchanged.
// DO NOT: 512-thread blocks; launch_bounds 2nd arg >2; uint4 reg prefetch
// arrays (R3); MAXC<32 or looser margin (R2); barrier-free L2 streaming
// (R7); wave-private chunks (R9); giant unrolled screens (R10 I$ blowup).
// ---------------------------------------------------------------------------
__global__ __launch_bounds__(256, 2) void vq_main(
    const float* __restrict__ z, const float* __restrict__ cb,
    const unsigned short* __restrict__ cb_bf, const float* __restrict__ ee,
    const float* __restrict__ mask,
    float* __restrict__ out_q, float* __restrict__ out_idx_f,
    float* __restrict__ out_loss, float* __restrict__ acc2,
    int* __restrict__ done_ctr, int nblocks, int K) {
  __shared__ __align__(16) unsigned short sbuf[2 * BUFW];    // 32 KB dbuf; buf0 doubles as z-stage (32 rows)
  __shared__ float znorm[TOK];
  __shared__ int   ccnt[TOK];
  __shared__ unsigned umin[TOK];                             // packed float gate
  __shared__ unsigned cand[TOK * MAXC];                      // 4 KB packed (dist22|idx10)
  __shared__ unsigned short bkbuf[TOK];
  __shared__ float red[8];
  __shared__ bool  last;

  const int t = threadIdx.x;
  const int n0 = blockIdx.x * TOK;
  const int wv = t >> 6, lane = t & 63;
  const int ts = wv & 1, cs = wv >> 1;
  const int quad = lane >> 4, l15 = lane & 15;
  const int q16 = t & 15;

  // ---- enmax partial (ee stays in GLOBAL; 4 KB is L1-resident) ----
  if (t < TOK) { ccnt[t] = 0; umin[t] = 0x7F7FFFFFu; }
  float em = fmaxf(fmaxf(ee[t], ee[t + 256]), fmaxf(ee[t + 512], ee[t + 768]));
  #pragma unroll
  for (int off = 32; off; off >>= 1) em = fmaxf(em, __shfl_xor(em, off, 64));
  if (lane == 0) red[wv] = em;

  // ---- stage z -> bf16 into buf0 rows 0..31 (swizzled); ||z|| ----
  #pragma unroll
  for (int pass = 0; pass < 2; ++pass) {
    int row = pass * 16 + (t >> 4);
    const float* zr = z + (size_t)(n0 + row) * 256;
    float ssq = 0.f;
    #pragma unroll
    for (int j = 0; j < 2; ++j) {
      float4 a = *reinterpret_cast<const float4*>(zr + q16 * 16 + j * 8);
      float4 b = *reinterpret_cast<const float4*>(zr + q16 * 16 + j * 8 + 4);
      ssq += a.x*a.x + a.y*a.y + a.z*a.z + a.w*a.w
           + b.x*b.x + b.y*b.y + b.z*b.z + b.w*b.w;
      int g = q16 * 2 + j;                       // logical granule 0..31
      *reinterpret_cast<uint4*>(&sbuf[row * 256 + ((g ^ (row & 7)) * 8)]) = pack8(a, b);
    }
    #pragma unroll
    for (int off = 1; off < 16; off <<= 1) ssq += __shfl_xor(ssq, off, 64);
    if (q16 == 0) znorm[row] = sqrtf(ssq);
  }
  __syncthreads();  // S1: z staged, red[] ready

  const float enmax = sqrtf(fmaxf(fmaxf(red[0], red[1]), fmaxf(red[2], red[3])));

  // ---- token fragments (B operand): wave owns token rows ts*16 + l15 ----
  bf16x8 tfrag[8];
  {
    int row = ts * 16 + l15;
    #pragma unroll
    for (int kk = 0; kk < 8; ++kk) {
      int g = (quad + kk * 4) ^ (row & 7);
      tfrag[kk] = *reinterpret_cast<const bf16x8*>(&sbuf[row * 256 + g * 8]);
    }
  }
  const float zn = znorm[ts * 16 + l15];
  const int tok = ts * 16 + l15;                 // this lane's token (C/D col)
  __syncthreads();  // S2: all token-frag loads done before chunk 0 overwrites buf0

  // ---- prologue: issue chunk 0 -> buf0 (async DMA), wait, publish ----
  {
    #pragma unroll
    for (int i = 0; i < 4; ++i) {
      int f = (wv * 4 + i) * 64 + lane;          // granule 0..1023
      int row = f >> 5, slot = f & 31;
      gload16(cb_bf + (size_t)row * 256 + ((slot ^ (row & 7)) * 8),
              &sbuf[(size_t)((wv * 4 + i) * 64) * 8]);
    }
  }
  asm volatile("s_waitcnt vmcnt(0)" ::: "memory");
  __syncthreads();  // S3: chunk 0 visible

  float am = 3.4e38f;                            // register gate (tightens only)

  // ---- chunk loop: 32 chunks x 32 codes, double-buffered async staging ----
  for (int lc = 0; lc < NCH; ++lc) {
    const int kbase = lc * CH;
    unsigned short* cur = &sbuf[(lc & 1) * BUFW];
    unsigned short* nxt = &sbuf[((lc + 1) & 1) * BUFW];
    if (lc < NCH - 1) {  // issue next chunk's DMA before compute
      const unsigned short* base = cb_bf + (size_t)(kbase + CH) * 256;
      #pragma unroll
      for (int i = 0; i < 4; ++i) {
        int f = (wv * 4 + i) * 64 + lane;
        int row = f >> 5, slot = f & 31;
        gload16(base + (size_t)row * 256 + ((slot ^ (row & 7)) * 8),
                nxt + (size_t)((wv * 4 + i) * 64) * 8);
      }
    }

    // hoist ee loads (global, L1) so latency hides under MFMA
    const int cb0 = kbase + cs * 16 + quad * 4;
    float4 ee4 = *reinterpret_cast<const float4*>(&ee[cb0]);

    // codes fragment (A operand): row = cs*16 + l15 within the chunk
    f32x4 acc = (f32x4){0.f, 0.f, 0.f, 0.f};
    const int arow = cs * 16 + l15;
    const unsigned short* abase = &cur[arow * 256];
    const int asw = arow & 7;
    __builtin_amdgcn_s_setprio(1);
    #pragma unroll
    for (int kk = 0; kk < 8; ++kk) {
      bf16x8 a = *reinterpret_cast<const bf16x8*>(abase + (((quad + kk * 4) ^ asw) * 8));
      // swapped operands: col = token, row = code
      acc = __builtin_amdgcn_mfma_f32_16x16x32_bf16(a, tfrag[kk], acc, 0, 0, 0);
    }
    __builtin_amdgcn_s_setprio(0);

    // register screen: lane holds 4 codes (cb0..cb0+3) of token `tok`
    float d0 = ee4.x - 2.f * acc[0];
    float d1 = ee4.y - 2.f * acc[1];
    float d2 = ee4.z - 2.f * acc[2];
    float d3 = ee4.w - 2.f * acc[3];
    float dm = fmaxf(fminf(fminf(d0, d1), fminf(d2, d3)), 0.f);
    atomicMin(&umin[tok], __float_as_uint(dm));   // 4-way same-address
    am = fminf(am, __uint_as_float(umin[tok]));   // gate read (in-order after publish)

    if (dm <= am + 1.5f + 0.002f * zn * enmax) {  // guard: most lanes skip admits
      if (d0 <= am + 1.5f + 0.002f * zn * sqrtf(ee4.x)) {
        int sl = atomicAdd(&ccnt[tok], 1);
        if (sl < MAXC) cand[tok * MAXC + sl] =
            (__float_as_uint(fmaxf(d0, 0.f)) & 0xFFFFFC00u) | (unsigned)(cb0);
      }
      if (d1 <= am + 1.5f + 0.002f * zn * sqrtf(ee4.y)) {
        int sl = atomicAdd(&ccnt[tok], 1);
        if (sl < MAXC) cand[tok * MAXC + sl] =
            (__float_as_uint(fmaxf(d1, 0.f)) & 0xFFFFFC00u) | (unsigned)(cb0 + 1);
      }
      if (d2 <= am + 1.5f + 0.002f * zn * sqrtf(ee4.z)) {
        int sl = atomicAdd(&ccnt[tok], 1);
        if (sl < MAXC) cand[tok * MAXC + sl] =
            (__float_as_uint(fmaxf(d2, 0.f)) & 0xFFFFFC00u) | (unsigned)(cb0 + 2);
      }
      if (d3 <= am + 1.5f + 0.002f * zn * sqrtf(ee4.w)) {
        int sl = atomicAdd(&ccnt[tok], 1);
        if (sl < MAXC) cand[tok * MAXC + sl] =
            (__float_as_uint(fmaxf(d3, 0.f)) & 0xFFFFFC00u) | (unsigned)(cb0 + 3);
      }
    }
    asm volatile("s_waitcnt vmcnt(0)" ::: "memory");  // next-chunk DMA landed
    __syncthreads();                                  // visible to all waves
  }

  // ---- phase 1: two-tier exact rescore (tokens wave-private: wv*8+it) ----
  for (int it = 0; it < 8; ++it) {
    int tk = wv * 8 + it;
    int n = n0 + tk;
    int cnt = ccnt[tk];
    int bk = 0;
    if (cnt > MAXC) {  // overflow safety net: exact scan of all K, 2-unrolled
      float4 zv = *reinterpret_cast<const float4*>(z + (size_t)n * 256 + lane * 4);
      float bs = 3.4e38f;
      for (int k = 0; k < K; k += 2) {
        float4 ca = *reinterpret_cast<const float4*>(cb + (size_t)k * 256 + lane * 4);
        float4 cbv = *reinterpret_cast<const float4*>(cb + (size_t)(k + 1) * 256 + lane * 4);
        float pa = zv.x * ca.x + zv.y * ca.y + zv.z * ca.z + zv.w * ca.w;
        float pb = zv.x * cbv.x + zv.y * cbv.y + zv.z * cbv.z + zv.w * cbv.w;
        #pragma unroll
        for (int off = 32; off; off >>= 1) {
          pa += __shfl_xor(pa, off, 64);
          pb += __shfl_xor(pb, off, 64);
        }
        float sa = ee[k] - 2.f * pa;
        float sb = ee[k + 1] - 2.f * pb;
        if (sa < bs) { bs = sa; bk = k; }
        if (sb < bs) { bs = sb; bk = k + 1; }
      }
    } else {
      // tier 1: flag candidates within margin of the exact screen-min
      float thr = __uint_as_float(umin[tk]) + 1.5f + 0.002f * znorm[tk] * enmax;
      int c = (lane < cnt) ? lane : 0;
      unsigned pe = cand[tk * MAXC + c];
      bool flag = (lane < cnt) && (__uint_as_float(pe & 0xFFFFFC00u) <= thr);
      unsigned long long msk = __ballot(flag);
      if (__popcll(msk) == 1) {
        int cc = __ffsll((long long)msk) - 1;
        bk = (int)(cand[tk * MAXC + cc] & 1023u);   // unique in-margin == argmin
      } else {
        // tier 2: 4-way-unrolled exact fp32 rescore over all cnt
        float4 zv = *reinterpret_cast<const float4*>(z + (size_t)n * 256 + lane * 4);
        float bs = 3.4e38f; bk = 1 << 29;
        int cc = 0;
        for (; cc + 4 <= cnt; cc += 4) {
          int k0 = cand[tk * MAXC + cc]     & 1023;
          int k1 = cand[tk * MAXC + cc + 1] & 1023;
          int k2 = cand[tk * MAXC + cc + 2] & 1023;
          int k3 = cand[tk * MAXC + cc + 3] & 1023;
          float4 e0 = *reinterpret_cast<const float4*>(cb + (size_t)k0 * 256 + lane * 4);
          float4 e1 = *reinterpret_cast<const float4*>(cb + (size_t)k1 * 256 + lane * 4);
          float4 e2 = *reinterpret_cast<const float4*>(cb + (size_t)k2 * 256 + lane * 4);
          float4 e3 = *reinterpret_cast<const float4*>(cb + (size_t)k3 * 256 + lane * 4);
          float p0 = zv.x * e0.x + zv.y * e0.y + zv.z * e0.z + zv.w * e0.w;
          float p1 = zv.x * e1.x + zv.y * e1.y + zv.z * e1.z + zv.w * e1.w;
          float p2 = zv.x * e2.x + zv.y * e2.y + zv.z * e2.z + zv.w * e2.w;
          float p3 = zv.x * e3.x + zv.y * e3.y + zv.z * e3.z + zv.w * e3.w;
          #pragma unroll
          for (int off = 32; off; off >>= 1) {   // 4 independent reduce chains
            p0 += __shfl_xor(p0, off, 64);
            p1 += __shfl_xor(p1, off, 64);
            p2 += __shfl_xor(p2, off, 64);
            p3 += __shfl_xor(p3, off, 64);
          }
          float s0 = ee[k0] - 2.f * p0;
          float s1 = ee[k1] - 2.f * p1;
          float s2 = ee[k2] - 2.f * p2;
          float s3 = ee[k3] - 2.f * p3;
          if (s0 < bs || (s0 == bs && k0 < bk)) { bs = s0; bk = k0; }
          if (s1 < bs || (s1 == bs && k1 < bk)) { bs = s1; bk = k1; }
          if (s2 < bs || (s2 == bs && k2 < bk)) { bs = s2; bk = k2; }
          if (s3 < bs || (s3 == bs && k3 < bk)) { bs = s3; bk = k3; }
        }
        for (; cc < cnt; ++cc) {
          int k = cand[tk * MAXC + cc] & 1023;
          float4 ev = *reinterpret_cast<const float4*>(cb + (size_t)k * 256 + lane * 4);
          float dp = zv.x * ev.x + zv.y * ev.y + zv.z * ev.z + zv.w * ev.w;
          #pragma unroll
          for (int off = 32; off; off >>= 1) dp += __shfl_xor(dp, off, 64);
          float s = ee[k] - 2.f * dp;   // identical on all lanes
          if (s < bs || (s == bs && k < bk)) { bs = s; bk = k; }
        }
      }
    }
    bkbuf[tk] = (unsigned short)bk;
  }

  // ---- phase 2: outputs + loss, 2 tokens in flight ----
  float lsum = 0.f, msum = 0.f;
  for (int it = 0; it < 8; it += 2) {
    int tokA = wv * 8 + it, tokB = tokA + 1;
    int na = n0 + tokA, nb = n0 + tokB;
    int ba = bkbuf[tokA], bb = bkbuf[tokB];
    float4 za = *reinterpret_cast<const float4*>(z + (size_t)na * 256 + lane * 4);
    float4 zb = *reinterpret_cast<const float4*>(z + (size_t)nb * 256 + lane * 4);
    float4 qa = *reinterpret_cast<const float4*>(cb + (size_t)ba * 256 + lane * 4);
    float4 qb = *reinterpret_cast<const float4*>(cb + (size_t)bb * 256 + lane * 4);
    float ma = mask[na], mb = mask[nb];
    float4 oa; oa.x = qa.x * ma; oa.y = qa.y * ma; oa.z = qa.z * ma; oa.w = qa.w * ma;
    float4 ob; ob.x = qb.x * mb; ob.y = qb.y * mb; ob.z = qb.z * mb; ob.w = qb.w * mb;
    *reinterpret_cast<float4*>(out_q + (size_t)na * 256 + lane * 4) = oa;
    *reinterpret_cast<float4*>(out_q + (size_t)nb * 256 + lane * 4) = ob;
    float dxa = za.x - qa.x, dya = za.y - qa.y, dza = za.z - qa.z, dwa = za.w - qa.w;
    float dxb = zb.x - qb.x, dyb = zb.y - qb.y, dzb = zb.z - qb.z, dwb = zb.w - qb.w;
    lsum = fmaf(ma, dxa * dxa + dya * dya + dza * dza + dwa * dwa, lsum);
    lsum = fmaf(mb, dxb * dxb + dyb * dyb + dzb * dzb + dwb * dwb, lsum);
    if (lane == 0) {
      msum += ma + mb;
      out_idx_f[na] = (ma > 0.f) ? (float)ba : 0.f;
      out_idx_f[nb] = (mb > 0.f) ? (float)bb : 0.f;
    }
  }
  #pragma unroll
  for (int off = 32; off; off >>= 1) lsum += __shfl_down(lsum, off, 64);
  if (lane == 0) { red[wv] = lsum; red[4 + wv] = msum; }
  __syncthreads();
  if (t == 0) {
    atomicAdd(&acc2[0], red[0] + red[1] + red[2] + red[3]);
    atomicAdd(&acc2[1], red[4] + red[5] + red[6] + red[7]);
    __threadfence();
    int prev = atomicAdd(done_ctr, 1);
    last = (prev == nblocks - 1);
  }
  __syncthreads();
  if (last && t == 0) {
    float s  = atomicAdd(&acc2[0], 0.0f);
    float nv = atomicAdd(&acc2[1], 0.0f);
    out_loss[0] = (nv > 0.f) ? (0.25f * s / (nv * 256.0f)) : 0.0f;
  }
}

// ---------------------------------------------------------------------------
extern "C" void kernel_launch(void* const* d_in, const int* in_sizes, int n_in,
                              void* d_out, int out_size, void* d_ws, size_t ws_size,
                              hipStream_t stream) {
  const float* z    = (const float*)d_in[0];  // (N, 256)
  const float* mask = (const float*)d_in[1];  // (N,)
  const float* cb   = (const float*)d_in[2];  // (K, 256)
  const int N = in_sizes[1];                  // 32768
  const int D = 256;
  const int K = in_sizes[2] / D;              // 1024

  float* wsf  = (float*)d_ws;
  float* acc2 = wsf;                          // 2 floats
  int*   dctr = (int*)(wsf + 2);              // 1 int
  float* ee   = wsf + 8;                      // K floats
  unsigned short* cb_bf = (unsigned short*)(ee + K);  // K*256 bf16

  float* out_q     = (float*)d_out;           // N*D
  float* out_loss  = out_q + (size_t)N * D;   // 1
  float* out_idx_f = out_loss + 1;            // N

  vq_prep<<<(K + 3) / 4, 256, 0, stream>>>(cb, cb_bf, ee, acc2, dctr, K);
  vq_main<<<N / TOK, 256, 0, stream>>>(z, cb, cb_bf, ee, mask, out_q,
                                       out_idx_f, out_loss, acc2, dctr, N / TOK, K);
}